// Round 1
// baseline (318.161 us; speedup 1.0000x reference)
//
#include <hip/hip_runtime.h>
#include <stdint.h>

#define BR 262144
#define NTAB 17
#define MAXR 512
#define DIN 272
#define AS0 296   // LDS row stride (bf16 elems) for layer0 (K padded to 288)
#define ASM 264   // LDS row stride for mid layers (K=256)
#define BNEPS 1e-5f

typedef __attribute__((ext_vector_type(8))) short short8;
typedef __attribute__((ext_vector_type(4))) float f32x4;
typedef __attribute__((ext_vector_type(4))) unsigned short ushort4w;

__device__ __forceinline__ unsigned short f2bf(float f) {
  union { float f; unsigned u; } v; v.f = f;
  return (unsigned short)((v.u + 0x7FFFu + ((v.u >> 16) & 1u)) >> 16);
}
__device__ __forceinline__ float bf2f(unsigned short h) {
  union { unsigned u; float f; } v; v.u = ((unsigned)h) << 16;
  return v.f;
}

// ---------- prep: pack W0 (f32 [272][256]) -> bf16 MFMA B-fragments, zero stats ----------
__global__ void k_prep0(const float* __restrict__ W0, unsigned short* __restrict__ pW0,
                        float* __restrict__ stats) {
  int tid = blockIdx.x * blockDim.x + threadIdx.x;
  int nth = gridDim.x * blockDim.x;
  for (int i = tid; i < 1280; i += nth) stats[i] = 0.f;
  for (int e = tid; e < 9 * 16 * 64; e += nth) {
    int l = e & 63, f = e >> 6;
    int nf = f & 15, ks = f >> 4;
    int col = nf * 16 + (l & 15);
    int kb = ks * 32 + ((l >> 4) << 3);
    unsigned short tmp[8];
#pragma unroll
    for (int j = 0; j < 8; j++) {
      int k = kb + j;
      tmp[j] = f2bf(k < DIN ? W0[k * 256 + col] : 0.f);
    }
    *(short8*)&pW0[(size_t)e * 8] = *(short8*)tmp;
  }
}

// ---------- fold BN(layer l) into W(l+1): pW = pack(diag(a)W), bOut = b + c*W ----------
template <int KP, int NP>
__global__ void k_fold(const float* __restrict__ gsum, const float* __restrict__ gsq,
                       const float* __restrict__ g, const float* __restrict__ be,
                       const float* __restrict__ W, const float* __restrict__ b,
                       unsigned short* __restrict__ pW, float* __restrict__ bOut) {
  __shared__ float sa[KP], sc[KP];
  int tid = threadIdx.x;
  if (tid < KP) {
    float mu = gsum[tid] * (1.f / BR);
    float var = fmaxf(gsq[tid] * (1.f / BR) - mu * mu, 0.f);
    float a = g[tid] * rsqrtf(var + BNEPS);
    sa[tid] = a;
    sc[tid] = be[tid] - mu * a;
  }
  __syncthreads();
  const int NFT = NP / 16;
  const int ENT = (KP / 32) * NFT * 64;
  for (int e = tid; e < ENT; e += blockDim.x) {
    int l = e & 63, f = e >> 6;
    int nf = f % NFT, ks = f / NFT;
    int col = nf * 16 + (l & 15);
    int kb = ks * 32 + ((l >> 4) << 3);
    unsigned short tmp[8];
#pragma unroll
    for (int j = 0; j < 8; j++) {
      int k = kb + j;
      tmp[j] = f2bf(sa[k] * W[k * NP + col]);
    }
    *(short8*)&pW[(size_t)e * 8] = *(short8*)tmp;
  }
  if (tid < NP) {
    float s = b[tid];
    for (int k = 0; k < KP; k++) s += sc[k] * W[k * NP + tid];
    bOut[tid] = s;
  }
}

// ---------- fold BN(layer2) into Wout ----------
__global__ void k_foldout(const float* __restrict__ gsum, const float* __restrict__ gsq,
                          const float* __restrict__ g, const float* __restrict__ be,
                          const float* __restrict__ Wout, const float* __restrict__ bout,
                          float* __restrict__ woutp, float* __restrict__ boutp) {
  __shared__ float red[128];
  int tid = threadIdx.x;  // 128 threads
  float mu = gsum[tid] * (1.f / BR);
  float var = fmaxf(gsq[tid] * (1.f / BR) - mu * mu, 0.f);
  float a = g[tid] * rsqrtf(var + BNEPS);
  float c = be[tid] - mu * a;
  float w = Wout[tid];
  woutp[tid] = a * w;
  red[tid] = c * w;
  __syncthreads();
  for (int s = 64; s > 0; s >>= 1) {
    if (tid < s) red[tid] += red[tid + s];
    __syncthreads();
  }
  if (tid == 0) boutp[0] = red[0] + bout[0];
}

// ---------- shared GEMM body: As (LDS, 128 rows x AST bf16) @ pW -> relu -> Y + stats ----------
// swapped-operand MFMA: acc layout per frag: row = lane&15, col = (lane>>4)*4 + j
template <int KSTEPS, int N, int AST, int MF>
__device__ __forceinline__ void gemm_body(const unsigned short* As, const unsigned short* __restrict__ pW,
                                          const float* __restrict__ bias, unsigned short* __restrict__ Y,
                                          int brow, float* ssum, float* ssq,
                                          float* __restrict__ gsum, float* __restrict__ gsq) {
  const int tid = threadIdx.x;
  const int lane = tid & 63, wave = tid >> 6;
  const int WC = N / 64;
  const int wc = wave % WC, wr = wave / WC;
  const int wrow = wr * (MF * 16);
  const int wcolf = wc * 4;  // column fragment base index
  const int arow = lane & 15;
  const int koff = (lane >> 4) << 3;

  f32x4 zero4 = {0.f, 0.f, 0.f, 0.f};
  f32x4 acc[MF][4];
#pragma unroll
  for (int mf = 0; mf < MF; mf++)
#pragma unroll
    for (int nf = 0; nf < 4; nf++) acc[mf][nf] = zero4;

#pragma unroll
  for (int ks = 0; ks < KSTEPS; ks++) {
    short8 a[MF], bfr[4];
#pragma unroll
    for (int mf = 0; mf < MF; mf++)
      a[mf] = *(const short8*)&As[(wrow + mf * 16 + arow) * AST + ks * 32 + koff];
#pragma unroll
    for (int nf = 0; nf < 4; nf++)
      bfr[nf] = *(const short8*)&pW[(size_t)((ks * (N / 16) + wcolf + nf) * 64 + lane) * 8];
#pragma unroll
    for (int mf = 0; mf < MF; mf++)
#pragma unroll
      for (int nf = 0; nf < 4; nf++)
        acc[mf][nf] = __builtin_amdgcn_mfma_f32_16x16x32_bf16(bfr[nf], a[mf], acc[mf][nf], 0, 0, 0);
  }

  // epilogue: bias + relu + bf16 store (8B/lane) + column stats
  const int grp = lane >> 4;
#pragma unroll
  for (int nf = 0; nf < 4; nf++) {
    const int c0 = (wcolf + nf) * 16 + grp * 4;
    f32x4 bb = *(const f32x4*)&bias[c0];
    float s[4] = {0.f, 0.f, 0.f, 0.f}, q[4] = {0.f, 0.f, 0.f, 0.f};
#pragma unroll
    for (int mf = 0; mf < MF; mf++) {
      const int r = brow + wrow + mf * 16 + arow;
      unsigned short o[4];
#pragma unroll
      for (int j = 0; j < 4; j++) {
        float v = fmaxf(acc[mf][nf][j] + bb[j], 0.f);
        o[j] = f2bf(v);
        s[j] += v;
        q[j] += v * v;
      }
      *(ushort4w*)&Y[(size_t)r * 256 + c0] = *(ushort4w*)o;
    }
#pragma unroll
    for (int d = 1; d < 16; d <<= 1) {
#pragma unroll
      for (int j = 0; j < 4; j++) {
        s[j] += __shfl_xor(s[j], d, 64);
        q[j] += __shfl_xor(q[j], d, 64);
      }
    }
    if ((lane & 15) == 0) {
#pragma unroll
      for (int j = 0; j < 4; j++) {
        atomicAdd(&ssum[c0 + j], s[j]);
        atomicAdd(&ssq[c0 + j], q[j]);
      }
    }
  }
  __syncthreads();
  if (tid < N) {
    atomicAdd(&gsum[tid], ssum[tid]);
    atomicAdd(&gsq[tid], ssq[tid]);
  }
}

// ---------- layer 0: embedding gather + GEMM ----------
__global__ void k_gemm0(const int* __restrict__ x, const float* __restrict__ tables,
                        const unsigned short* __restrict__ pW, const float* __restrict__ bias,
                        unsigned short* __restrict__ Y, float* __restrict__ gsum, float* __restrict__ gsq) {
  __shared__ unsigned short As[128 * AS0];
  __shared__ float ssum[256], ssq[256];
  const int tid = threadIdx.x;
  if (tid < 256) { ssum[tid] = 0.f; ssq[tid] = 0.f; }
  const int brow = blockIdx.x * 128;
  // gather: 128 rows x 17 tables, each 16 f32 -> bf16 into LDS
  for (int t = tid; t < 128 * NTAB; t += 512) {
    int row = t / NTAB;
    int tbl = t - row * NTAB;
    int idx = x[brow * NTAB + t];
    const float* src = tables + ((size_t)tbl * MAXR + idx) * 16;
    f32x4 v0 = ((const f32x4*)src)[0];
    f32x4 v1 = ((const f32x4*)src)[1];
    f32x4 v2 = ((const f32x4*)src)[2];
    f32x4 v3 = ((const f32x4*)src)[3];
    unsigned short tmp[16];
#pragma unroll
    for (int j = 0; j < 4; j++) {
      tmp[j] = f2bf(v0[j]);
      tmp[4 + j] = f2bf(v1[j]);
      tmp[8 + j] = f2bf(v2[j]);
      tmp[12 + j] = f2bf(v3[j]);
    }
    unsigned base = row * AS0 + tbl * 16;
    *(short8*)&As[base] = *(short8*)&tmp[0];
    *(short8*)&As[base + 8] = *(short8*)&tmp[8];
  }
  // zero K padding cols 272..295
  short8 z8 = {0, 0, 0, 0, 0, 0, 0, 0};
  for (int t = tid; t < 128; t += 512) {
    *(short8*)&As[t * AS0 + 272] = z8;
    *(short8*)&As[t * AS0 + 280] = z8;
    *(short8*)&As[t * AS0 + 288] = z8;
  }
  __syncthreads();
  gemm_body<9, 256, AS0, 4>(As, pW, bias, Y, brow, ssum, ssq, gsum, gsq);
}

// ---------- mid layers: A from Y (bf16), in-place write ----------
template <int N, int MF>
__global__ void k_gemm_mid(const unsigned short* __restrict__ Yin,
                           const unsigned short* __restrict__ pW, const float* __restrict__ bias,
                           unsigned short* __restrict__ Y, float* __restrict__ gsum, float* __restrict__ gsq) {
  __shared__ unsigned short As[128 * ASM];
  __shared__ float ssum[256], ssq[256];
  const int tid = threadIdx.x;
  if (tid < 256) { ssum[tid] = 0.f; ssq[tid] = 0.f; }
  const int brow = blockIdx.x * 128;
  // stage 128 rows x 256 cols bf16 (4096 x 16B chunks)
  for (int i = tid; i < 128 * 32; i += 512) {
    int row = i >> 5, c16 = i & 31;
    short8 v = *(const short8*)&Yin[((size_t)(brow + row)) * 256 + c16 * 8];
    *(short8*)&As[row * ASM + c16 * 8] = v;
  }
  __syncthreads();
  gemm_body<8, N, ASM, MF>(As, pW, bias, Y, brow, ssum, ssq, gsum, gsq);
}

// ---------- final dot: out = Y2 . wout' + bout' ----------
__global__ void k_out(const unsigned short* __restrict__ Y, const float* __restrict__ woutp,
                      const float* __restrict__ boutp, float* __restrict__ out) {
  __shared__ float w[128];
  const int tid = threadIdx.x;
  if (tid < 128) w[tid] = woutp[tid];
  __syncthreads();
  const int lane = tid & 63, wave = tid >> 6;
  const int sub = lane & 7, rloc = lane >> 3;
  const int row = blockIdx.x * 32 + wave * 8 + rloc;
  const unsigned short* yr = &Y[(size_t)row * 256 + sub * 16];
  short8 v0 = *(const short8*)yr;
  short8 v1 = *(const short8*)(yr + 8);
  float acc = 0.f;
#pragma unroll
  for (int j = 0; j < 8; j++) acc += bf2f((unsigned short)v0[j]) * w[sub * 16 + j];
#pragma unroll
  for (int j = 0; j < 8; j++) acc += bf2f((unsigned short)v1[j]) * w[sub * 16 + 8 + j];
  acc += __shfl_xor(acc, 1, 64);
  acc += __shfl_xor(acc, 2, 64);
  acc += __shfl_xor(acc, 4, 64);
  if (sub == 0) out[row] = acc + boutp[0];
}

extern "C" void kernel_launch(void* const* d_in, const int* in_sizes, int n_in,
                              void* d_out, int out_size, void* d_ws, size_t ws_size,
                              hipStream_t stream) {
  const int* x = (const int*)d_in[0];
  const float* tables = (const float*)d_in[1];
  const float* W0 = (const float*)d_in[2];
  const float* b0 = (const float*)d_in[3];
  const float* g0 = (const float*)d_in[4];
  const float* be0 = (const float*)d_in[5];
  const float* W1 = (const float*)d_in[6];
  const float* b1 = (const float*)d_in[7];
  const float* g1 = (const float*)d_in[8];
  const float* be1 = (const float*)d_in[9];
  const float* W2 = (const float*)d_in[10];
  const float* b2 = (const float*)d_in[11];
  const float* g2 = (const float*)d_in[12];
  const float* be2 = (const float*)d_in[13];
  const float* Wout = (const float*)d_in[14];
  const float* bout = (const float*)d_in[15];
  float* out = (float*)d_out;

  char* ws = (char*)d_ws;
  unsigned short* Y = (unsigned short*)ws;
  size_t off = (size_t)BR * 256 * 2;             // 134,217,728
  float* stats = (float*)(ws + off);             // 1280 f32
  off += 5120;
  unsigned short* pW0 = (unsigned short*)(ws + off); off += (size_t)9 * 16 * 64 * 8 * 2;   // 147456
  unsigned short* pW1 = (unsigned short*)(ws + off); off += (size_t)8 * 16 * 64 * 8 * 2;   // 131072
  unsigned short* pW2 = (unsigned short*)(ws + off); off += (size_t)8 * 8 * 64 * 8 * 2;    // 65536
  float* b1p = (float*)(ws + off); off += 1024;
  float* b2p = (float*)(ws + off); off += 512;
  float* woutp = (float*)(ws + off); off += 512;
  float* boutp = (float*)(ws + off); off += 256;

  float* sum0 = stats;
  float* sq0 = stats + 256;
  float* sum1 = stats + 512;
  float* sq1 = stats + 768;
  float* sum2 = stats + 1024;
  float* sq2 = stats + 1152;

  k_prep0<<<40, 256, 0, stream>>>(W0, pW0, stats);
  k_gemm0<<<BR / 128, 512, 0, stream>>>(x, tables, pW0, b0, Y, sum0, sq0);
  k_fold<256, 256><<<1, 1024, 0, stream>>>(sum0, sq0, g0, be0, W1, b1, pW1, b1p);
  k_gemm_mid<256, 4><<<BR / 128, 512, 0, stream>>>(Y, pW1, b1p, Y, sum1, sq1);
  k_fold<256, 128><<<1, 1024, 0, stream>>>(sum1, sq1, g1, be1, W2, b2, pW2, b2p);
  k_gemm_mid<128, 2><<<BR / 128, 512, 0, stream>>>(Y, pW2, b2p, Y, sum2, sq2);
  k_foldout<<<1, 128, 0, stream>>>(sum2, sq2, g2, be2, Wout, bout, woutp, boutp);
  k_out<<<BR / 32, 256, 0, stream>>>(Y, woutp, boutp, out);
}

// Round 3
// 258.832 us; speedup vs baseline: 1.2292x; 1.2292x over previous
//
#include <hip/hip_runtime.h>
#include <stdint.h>

#define BR 262144
#define NTAB 17
#define MAXR 512
#define DIN 272
#define AS0 296   // LDS row stride (bf16) layer0 (K padded to 288); also C-restage stride
#define ASM 264   // LDS row stride (bf16) mid layers (K=256); also C-restage stride
#define NCOPY 32
#define BNEPS 1e-5f

typedef __attribute__((ext_vector_type(8))) short short8;
typedef __attribute__((ext_vector_type(4))) float f32x4;
typedef __attribute__((ext_vector_type(4))) unsigned short ushort4w;

__device__ __forceinline__ unsigned short f2bf(float f) {
  union { float f; unsigned u; } v; v.f = f;
  return (unsigned short)((v.u + 0x7FFFu + ((v.u >> 16) & 1u)) >> 16);
}
__device__ __forceinline__ float bf2f(unsigned short h) {
  union { unsigned u; float f; } v; v.u = ((unsigned)h) << 16;
  return v.f;
}

// ---------- prep: pack W0 (f32 [272][256]) -> bf16 MFMA B-fragments, zero stats ----------
__global__ void k_prep0(const float* __restrict__ W0, unsigned short* __restrict__ pW0,
                        float* __restrict__ stats) {
  int tid = blockIdx.x * blockDim.x + threadIdx.x;
  int nth = gridDim.x * blockDim.x;
  for (int i = tid; i < NCOPY * 1280; i += nth) stats[i] = 0.f;
  for (int e = tid; e < 9 * 16 * 64; e += nth) {
    int l = e & 63, f = e >> 6;
    int nf = f & 15, ks = f >> 4;
    int col = nf * 16 + (l & 15);
    int kb = ks * 32 + ((l >> 4) << 3);
    unsigned short tmp[8];
#pragma unroll
    for (int j = 0; j < 8; j++) {
      int k = kb + j;
      tmp[j] = f2bf(k < DIN ? W0[k * 256 + col] : 0.f);
    }
    *(short8*)&pW0[(size_t)e * 8] = *(short8*)tmp;
  }
}

// ---------- fold BN(layer l) into W(l+1) ----------
template <int KP, int NP>
__global__ void k_fold(const float* __restrict__ stats, int offSum, int offSq,
                       const float* __restrict__ g, const float* __restrict__ be,
                       const float* __restrict__ W, const float* __restrict__ b,
                       unsigned short* __restrict__ pW, float* __restrict__ bOut) {
  __shared__ float sa[KP], sc[KP];
  int tid = threadIdx.x;  // 256
  if (tid < KP) {
    float s = 0.f, q = 0.f;
    for (int c = 0; c < NCOPY; c++) {
      s += stats[c * 1280 + offSum + tid];
      q += stats[c * 1280 + offSq + tid];
    }
    float mu = s * (1.f / BR);
    float var = fmaxf(q * (1.f / BR) - mu * mu, 0.f);
    float a = g[tid] * rsqrtf(var + BNEPS);
    sa[tid] = a;
    sc[tid] = be[tid] - mu * a;
  }
  __syncthreads();
  const int NFT = NP / 16;
  const int ENT = (KP / 32) * NFT * 64;
  for (int e = blockIdx.x * blockDim.x + tid; e < ENT; e += gridDim.x * blockDim.x) {
    int l = e & 63, f = e >> 6;
    int nf = f % NFT, ks = f / NFT;
    int col = nf * 16 + (l & 15);
    int kb = ks * 32 + ((l >> 4) << 3);
    unsigned short tmp[8];
#pragma unroll
    for (int j = 0; j < 8; j++) {
      int k = kb + j;
      tmp[j] = f2bf(sa[k] * W[k * NP + col]);
    }
    *(short8*)&pW[(size_t)e * 8] = *(short8*)tmp;
  }
  if (blockIdx.x == 0 && tid < NP) {
    float s = b[tid];
    for (int k = 0; k < KP; k++) s += sc[k] * W[k * NP + tid];
    bOut[tid] = s;
  }
}

// ---------- fold BN(layer2) into Wout ----------
__global__ void k_foldout(const float* __restrict__ stats, int offSum, int offSq,
                          const float* __restrict__ g, const float* __restrict__ be,
                          const float* __restrict__ Wout, const float* __restrict__ bout,
                          float* __restrict__ woutp, float* __restrict__ boutp) {
  __shared__ float red[128];
  int tid = threadIdx.x;  // 128 threads
  float s = 0.f, q = 0.f;
  for (int c = 0; c < NCOPY; c++) {
    s += stats[c * 1280 + offSum + tid];
    q += stats[c * 1280 + offSq + tid];
  }
  float mu = s * (1.f / BR);
  float var = fmaxf(q * (1.f / BR) - mu * mu, 0.f);
  float a = g[tid] * rsqrtf(var + BNEPS);
  float c = be[tid] - mu * a;
  float w = Wout[tid];
  woutp[tid] = a * w;
  red[tid] = c * w;
  __syncthreads();
  for (int st = 64; st > 0; st >>= 1) {
    if (tid < st) red[tid] += red[tid + st];
    __syncthreads();
  }
  if (tid == 0) boutp[0] = red[0] + bout[0];
}

// ---------- shared GEMM body: 64 rows x N cols per block, 256 threads (4 waves) ----------
// swapped-operand MFMA: acc frag: row = lane&15, col = (lane>>4)*4 + j
// C-restage reuses As at the SAME stride AST (bounds-exact; round-2 bug was a 270-stride overflow)
template <int KSTEPS, int N, int AST, int MF>
__device__ __forceinline__ void gemm_body(unsigned short* As, const unsigned short* __restrict__ pW,
                                          const float* __restrict__ bias, unsigned short* __restrict__ Y,
                                          int brow, float* ssum, float* ssq,
                                          float* __restrict__ gsum, float* __restrict__ gsq) {
  const int tid = threadIdx.x;
  const int lane = tid & 63, wave = tid >> 6;
  constexpr int WC = N / 64;          // waves along cols
  const int wc = wave % WC, wr = wave / WC;
  const int wrow = wr * (MF * 16);
  const int wcolf = wc * 4;
  const int arow = lane & 15;
  const int koff = (lane >> 4) << 3;
  const int grp = lane >> 4;

  f32x4 zero4 = {0.f, 0.f, 0.f, 0.f};
  f32x4 acc[MF][4];
#pragma unroll
  for (int mf = 0; mf < MF; mf++)
#pragma unroll
    for (int nf = 0; nf < 4; nf++) acc[mf][nf] = zero4;

  // depth-1 prefetch of b-fragments (global/L2, long latency)
  short8 bcur[4], bnxt[4];
#pragma unroll
  for (int nf = 0; nf < 4; nf++)
    bcur[nf] = *(const short8*)&pW[(size_t)((wcolf + nf) * 64 + lane) * 8];

#pragma unroll
  for (int ks = 0; ks < KSTEPS; ks++) {
    if (ks + 1 < KSTEPS) {
#pragma unroll
      for (int nf = 0; nf < 4; nf++)
        bnxt[nf] = *(const short8*)&pW[(size_t)(((ks + 1) * (N / 16) + wcolf + nf) * 64 + lane) * 8];
    }
#pragma unroll
    for (int mf = 0; mf < MF; mf++) {
      short8 am = *(const short8*)&As[(wrow + mf * 16 + arow) * AST + ks * 32 + koff];
#pragma unroll
      for (int nf = 0; nf < 4; nf++)
        acc[mf][nf] = __builtin_amdgcn_mfma_f32_16x16x32_bf16(bcur[nf], am, acc[mf][nf], 0, 0, 0);
    }
#pragma unroll
    for (int nf = 0; nf < 4; nf++) bcur[nf] = bnxt[nf];
  }

  __syncthreads();  // all As reads done; reuse As as C restage buffer (stride AST)

  // epilogue: bias + relu + stage bf16 to LDS + column stats in regs
#pragma unroll
  for (int nf = 0; nf < 4; nf++) {
    const int c0 = (wcolf + nf) * 16 + grp * 4;
    f32x4 bb = *(const f32x4*)&bias[c0];
    float s[4] = {0.f, 0.f, 0.f, 0.f}, q[4] = {0.f, 0.f, 0.f, 0.f};
#pragma unroll
    for (int mf = 0; mf < MF; mf++) {
      const int r = wrow + mf * 16 + arow;
      unsigned short o[4];
#pragma unroll
      for (int j = 0; j < 4; j++) {
        float v = fmaxf(acc[mf][nf][j] + bb[j], 0.f);
        o[j] = f2bf(v);
        s[j] += v;
        q[j] += v * v;
      }
      *(ushort4w*)&As[r * AST + c0] = *(ushort4w*)o;
    }
#pragma unroll
    for (int d = 1; d < 16; d <<= 1) {
#pragma unroll
      for (int j = 0; j < 4; j++) {
        s[j] += __shfl_xor(s[j], d, 64);
        q[j] += __shfl_xor(q[j], d, 64);
      }
    }
    if ((lane & 15) == 0) {
#pragma unroll
      for (int j = 0; j < 4; j++) {
        atomicAdd(&ssum[c0 + j], s[j]);
        atomicAdd(&ssq[c0 + j], q[j]);
      }
    }
  }
  __syncthreads();

  // coalesced row-major store from LDS (16B/lane) + per-block stats -> replicated copies
  constexpr int CH = N / 8;
  for (int i = tid; i < 64 * CH; i += 256) {
    int row = i / CH, ch = i % CH;
    *(short8*)&Y[(size_t)(brow + row) * 256 + ch * 8] = *(const short8*)&As[row * AST + ch * 8];
  }
  if (tid < N) {
    atomicAdd(&gsum[tid], ssum[tid]);
    atomicAdd(&gsq[tid], ssq[tid]);
  }
}

// ---------- layer 0: embedding gather + GEMM ----------
__global__ __launch_bounds__(256, 4) void k_gemm0(const int* __restrict__ x, const float* __restrict__ tables,
                        const unsigned short* __restrict__ pW, const float* __restrict__ bias,
                        unsigned short* __restrict__ Y, float* __restrict__ stats, int offSum, int offSq) {
  __shared__ unsigned short As[64 * AS0];
  __shared__ float ssum[256], ssq[256];
  const int tid = threadIdx.x;
  if (tid < 256) { ssum[tid] = 0.f; ssq[tid] = 0.f; }
  const int brow = blockIdx.x * 64;
  for (int t = tid; t < 64 * NTAB; t += 256) {
    int row = t / NTAB;
    int tbl = t - row * NTAB;
    int idx = x[brow * NTAB + t];
    const float* src = tables + ((size_t)tbl * MAXR + idx) * 16;
    f32x4 v0 = ((const f32x4*)src)[0];
    f32x4 v1 = ((const f32x4*)src)[1];
    f32x4 v2 = ((const f32x4*)src)[2];
    f32x4 v3 = ((const f32x4*)src)[3];
    unsigned short tmp[16];
#pragma unroll
    for (int j = 0; j < 4; j++) {
      tmp[j] = f2bf(v0[j]);
      tmp[4 + j] = f2bf(v1[j]);
      tmp[8 + j] = f2bf(v2[j]);
      tmp[12 + j] = f2bf(v3[j]);
    }
    unsigned base = row * AS0 + tbl * 16;
    *(short8*)&As[base] = *(short8*)&tmp[0];
    *(short8*)&As[base + 8] = *(short8*)&tmp[8];
  }
  short8 z8 = {0, 0, 0, 0, 0, 0, 0, 0};
  for (int t = tid; t < 64; t += 256) {
    *(short8*)&As[t * AS0 + 272] = z8;
    *(short8*)&As[t * AS0 + 280] = z8;
    *(short8*)&As[t * AS0 + 288] = z8;
  }
  __syncthreads();
  float* gsum = stats + (size_t)(blockIdx.x & (NCOPY - 1)) * 1280 + offSum;
  float* gsq  = stats + (size_t)(blockIdx.x & (NCOPY - 1)) * 1280 + offSq;
  gemm_body<9, 256, AS0, 4>(As, pW, bias, Y, brow, ssum, ssq, gsum, gsq);
}

// ---------- mid layers ----------
template <int N, int MF>
__global__ __launch_bounds__(256, 4) void k_gemm_mid(const unsigned short* __restrict__ Yin,
                           const unsigned short* __restrict__ pW, const float* __restrict__ bias,
                           unsigned short* __restrict__ Y, float* __restrict__ stats, int offSum, int offSq) {
  __shared__ unsigned short As[64 * ASM];
  __shared__ float ssum[256], ssq[256];
  const int tid = threadIdx.x;
  if (tid < 256) { ssum[tid] = 0.f; ssq[tid] = 0.f; }
  const int brow = blockIdx.x * 64;
  for (int i = tid; i < 64 * 32; i += 256) {
    int row = i >> 5, c16 = i & 31;
    short8 v = *(const short8*)&Yin[((size_t)(brow + row)) * 256 + c16 * 8];
    *(short8*)&As[row * ASM + c16 * 8] = v;
  }
  __syncthreads();
  float* gsum = stats + (size_t)(blockIdx.x & (NCOPY - 1)) * 1280 + offSum;
  float* gsq  = stats + (size_t)(blockIdx.x & (NCOPY - 1)) * 1280 + offSq;
  gemm_body<8, N, ASM, MF>(As, pW, bias, Y, brow, ssum, ssq, gsum, gsq);
}

// ---------- final dot ----------
__global__ void k_out(const unsigned short* __restrict__ Y, const float* __restrict__ woutp,
                      const float* __restrict__ boutp, float* __restrict__ out) {
  __shared__ float w[128];
  const int tid = threadIdx.x;
  if (tid < 128) w[tid] = woutp[tid];
  __syncthreads();
  const int lane = tid & 63, wave = tid >> 6;
  const int sub = lane & 7, rloc = lane >> 3;
  const int row = blockIdx.x * 32 + wave * 8 + rloc;
  const unsigned short* yr = &Y[(size_t)row * 256 + sub * 16];
  short8 v0 = *(const short8*)yr;
  short8 v1 = *(const short8*)(yr + 8);
  float acc = 0.f;
#pragma unroll
  for (int j = 0; j < 8; j++) acc += bf2f((unsigned short)v0[j]) * w[sub * 16 + j];
#pragma unroll
  for (int j = 0; j < 8; j++) acc += bf2f((unsigned short)v1[j]) * w[sub * 16 + 8 + j];
  acc += __shfl_xor(acc, 1, 64);
  acc += __shfl_xor(acc, 2, 64);
  acc += __shfl_xor(acc, 4, 64);
  if (sub == 0) out[row] = acc + boutp[0];
}

extern "C" void kernel_launch(void* const* d_in, const int* in_sizes, int n_in,
                              void* d_out, int out_size, void* d_ws, size_t ws_size,
                              hipStream_t stream) {
  const int* x = (const int*)d_in[0];
  const float* tables = (const float*)d_in[1];
  const float* W0 = (const float*)d_in[2];
  const float* b0 = (const float*)d_in[3];
  const float* g0 = (const float*)d_in[4];
  const float* be0 = (const float*)d_in[5];
  const float* W1 = (const float*)d_in[6];
  const float* b1 = (const float*)d_in[7];
  const float* g1 = (const float*)d_in[8];
  const float* be1 = (const float*)d_in[9];
  const float* W2 = (const float*)d_in[10];
  const float* b2 = (const float*)d_in[11];
  const float* g2 = (const float*)d_in[12];
  const float* be2 = (const float*)d_in[13];
  const float* Wout = (const float*)d_in[14];
  const float* bout = (const float*)d_in[15];
  float* out = (float*)d_out;

  char* ws = (char*)d_ws;
  unsigned short* Y = (unsigned short*)ws;
  size_t off = (size_t)BR * 256 * 2;  // 134,217,728
  unsigned short* pW0 = (unsigned short*)(ws + off); off += (size_t)9 * 16 * 64 * 8 * 2;
  unsigned short* pW1 = (unsigned short*)(ws + off); off += (size_t)8 * 16 * 64 * 8 * 2;
  unsigned short* pW2 = (unsigned short*)(ws + off); off += (size_t)8 * 8 * 64 * 8 * 2;
  float* b1p = (float*)(ws + off); off += 1024;
  float* b2p = (float*)(ws + off); off += 512;
  float* woutp = (float*)(ws + off); off += 512;
  float* boutp = (float*)(ws + off); off += 256;
  float* stats = (float*)(ws + off); off += (size_t)NCOPY * 1280 * 4;

  // stats offsets within each 1280-float copy
  const int oS0 = 0, oQ0 = 256, oS1 = 512, oQ1 = 768, oS2 = 1024, oQ2 = 1152;

  k_prep0<<<64, 256, 0, stream>>>(W0, pW0, stats);
  k_gemm0<<<BR / 64, 256, 0, stream>>>(x, tables, pW0, b0, Y, stats, oS0, oQ0);
  k_fold<256, 256><<<16, 256, 0, stream>>>(stats, oS0, oQ0, g0, be0, W1, b1, pW1, b1p);
  k_gemm_mid<256, 4><<<BR / 64, 256, 0, stream>>>(Y, pW1, b1p, Y, stats, oS1, oQ1);
  k_fold<256, 128><<<16, 256, 0, stream>>>(stats, oS1, oQ1, g1, be1, W2, b2, pW2, b2p);
  k_gemm_mid<128, 2><<<BR / 64, 256, 0, stream>>>(Y, pW2, b2p, Y, stats, oS2, oQ2);
  k_foldout<<<1, 128, 0, stream>>>(stats, oS2, oQ2, g2, be2, Wout, bout, woutp, boutp);
  k_out<<<BR / 32, 256, 0, stream>>>(Y, woutp, boutp, out);
}

// Round 4
// 251.084 us; speedup vs baseline: 1.2672x; 1.0309x over previous
//
#include <hip/hip_runtime.h>
#include <stdint.h>

#define BR 262144
#define NTAB 17
#define MAXR 512
#define DIN 272
#define AS0 296   // LDS row stride (bf16) layer0 (K padded to 288); also C-restage stride
#define ASM 264   // LDS row stride (bf16) mid layers (K=256); also C-restage stride
#define NCOPY 32
#define BNEPS 1e-5f

typedef __attribute__((ext_vector_type(8))) short short8;
typedef __attribute__((ext_vector_type(4))) float f32x4;
typedef __attribute__((ext_vector_type(4))) unsigned short ushort4w;

__device__ __forceinline__ unsigned short f2bf(float f) {
  union { float f; unsigned u; } v; v.f = f;
  return (unsigned short)((v.u + 0x7FFFu + ((v.u >> 16) & 1u)) >> 16);
}
__device__ __forceinline__ float bf2f(unsigned short h) {
  union { unsigned u; float f; } v; v.u = ((unsigned)h) << 16;
  return v.f;
}

// ---------- prep: tables f32 -> bf16; pack W0 -> MFMA B-frags; zero stats ----------
__global__ void k_prep0(const float* __restrict__ W0, const float* __restrict__ tables,
                        unsigned short* __restrict__ pW0, unsigned short* __restrict__ tb,
                        float* __restrict__ stats) {
  int tid = blockIdx.x * blockDim.x + threadIdx.x;
  int nth = gridDim.x * blockDim.x;
  for (int i = tid; i < NCOPY * 1280; i += nth) stats[i] = 0.f;
  // tables: 17*512*16 = 139264 f32 -> bf16, 8 elems per task
  for (int e = tid; e < 17408; e += nth) {
    const float* src = tables + (size_t)e * 8;
    f32x4 v0 = ((const f32x4*)src)[0];
    f32x4 v1 = ((const f32x4*)src)[1];
    unsigned short tmp[8];
#pragma unroll
    for (int j = 0; j < 4; j++) { tmp[j] = f2bf(v0[j]); tmp[4 + j] = f2bf(v1[j]); }
    *(short8*)&tb[(size_t)e * 8] = *(short8*)tmp;
  }
  for (int e = tid; e < 9 * 16 * 64; e += nth) {
    int l = e & 63, f = e >> 6;
    int nf = f & 15, ks = f >> 4;
    int col = nf * 16 + (l & 15);
    int kb = ks * 32 + ((l >> 4) << 3);
    unsigned short tmp[8];
#pragma unroll
    for (int j = 0; j < 8; j++) {
      int k = kb + j;
      tmp[j] = f2bf(k < DIN ? W0[k * 256 + col] : 0.f);
    }
    *(short8*)&pW0[(size_t)e * 8] = *(short8*)tmp;
  }
}

// ---------- fold BN(layer l) into W(l+1) ----------
template <int KP, int NP>
__global__ void k_fold(const float* __restrict__ stats, int offSum, int offSq,
                       const float* __restrict__ g, const float* __restrict__ be,
                       const float* __restrict__ W, const float* __restrict__ b,
                       unsigned short* __restrict__ pW, float* __restrict__ bOut) {
  __shared__ float sa[KP], sc[KP];
  int tid = threadIdx.x;  // 256
  if (tid < KP) {
    float s = 0.f, q = 0.f;
    for (int c = 0; c < NCOPY; c++) {
      s += stats[c * 1280 + offSum + tid];
      q += stats[c * 1280 + offSq + tid];
    }
    float mu = s * (1.f / BR);
    float var = fmaxf(q * (1.f / BR) - mu * mu, 0.f);
    float a = g[tid] * rsqrtf(var + BNEPS);
    sa[tid] = a;
    sc[tid] = be[tid] - mu * a;
  }
  __syncthreads();
  const int NFT = NP / 16;
  const int ENT = (KP / 32) * NFT * 64;
  for (int e = blockIdx.x * blockDim.x + tid; e < ENT; e += gridDim.x * blockDim.x) {
    int l = e & 63, f = e >> 6;
    int nf = f % NFT, ks = f / NFT;
    int col = nf * 16 + (l & 15);
    int kb = ks * 32 + ((l >> 4) << 3);
    unsigned short tmp[8];
#pragma unroll
    for (int j = 0; j < 8; j++) {
      int k = kb + j;
      tmp[j] = f2bf(sa[k] * W[k * NP + col]);
    }
    *(short8*)&pW[(size_t)e * 8] = *(short8*)tmp;
  }
  if (blockIdx.x == 0 && tid < NP) {
    float s = b[tid];
    for (int k = 0; k < KP; k++) s += sc[k] * W[k * NP + tid];
    bOut[tid] = s;
  }
}

// ---------- fold BN(layer2) into Wout ----------
__global__ void k_foldout(const float* __restrict__ stats, int offSum, int offSq,
                          const float* __restrict__ g, const float* __restrict__ be,
                          const float* __restrict__ Wout, const float* __restrict__ bout,
                          float* __restrict__ woutp, float* __restrict__ boutp) {
  __shared__ float red[128];
  int tid = threadIdx.x;  // 128 threads
  float s = 0.f, q = 0.f;
  for (int c = 0; c < NCOPY; c++) {
    s += stats[c * 1280 + offSum + tid];
    q += stats[c * 1280 + offSq + tid];
  }
  float mu = s * (1.f / BR);
  float var = fmaxf(q * (1.f / BR) - mu * mu, 0.f);
  float a = g[tid] * rsqrtf(var + BNEPS);
  float c = be[tid] - mu * a;
  float w = Wout[tid];
  woutp[tid] = a * w;
  red[tid] = c * w;
  __syncthreads();
  for (int st = 64; st > 0; st >>= 1) {
    if (tid < st) red[tid] += red[tid + st];
    __syncthreads();
  }
  if (tid == 0) boutp[0] = red[0] + bout[0];
}

// ---------- shared GEMM body: 64 rows x N cols per block, 256 threads (4 waves) ----------
// swapped-operand MFMA: acc frag: row = lane&15, col = (lane>>4)*4 + j
template <int KSTEPS, int N, int AST, int MF>
__device__ __forceinline__ void gemm_body(unsigned short* As, const unsigned short* __restrict__ pW,
                                          const float* __restrict__ bias, unsigned short* __restrict__ Y,
                                          int brow, float* ssum, float* ssq,
                                          float* __restrict__ gsum, float* __restrict__ gsq) {
  const int tid = threadIdx.x;
  const int lane = tid & 63, wave = tid >> 6;
  constexpr int WC = N / 64;          // waves along cols
  const int wc = wave % WC, wr = wave / WC;
  const int wrow = wr * (MF * 16);
  const int wcolf = wc * 4;
  const int arow = lane & 15;
  const int koff = (lane >> 4) << 3;
  const int grp = lane >> 4;

  f32x4 zero4 = {0.f, 0.f, 0.f, 0.f};
  f32x4 acc[MF][4];
#pragma unroll
  for (int mf = 0; mf < MF; mf++)
#pragma unroll
    for (int nf = 0; nf < 4; nf++) acc[mf][nf] = zero4;

  // depth-1 prefetch of b-fragments (global/L2, long latency)
  short8 bcur[4], bnxt[4];
#pragma unroll
  for (int nf = 0; nf < 4; nf++)
    bcur[nf] = *(const short8*)&pW[(size_t)((wcolf + nf) * 64 + lane) * 8];

#pragma unroll
  for (int ks = 0; ks < KSTEPS; ks++) {
    if (ks + 1 < KSTEPS) {
#pragma unroll
      for (int nf = 0; nf < 4; nf++)
        bnxt[nf] = *(const short8*)&pW[(size_t)(((ks + 1) * (N / 16) + wcolf + nf) * 64 + lane) * 8];
    }
#pragma unroll
    for (int mf = 0; mf < MF; mf++) {
      short8 am = *(const short8*)&As[(wrow + mf * 16 + arow) * AST + ks * 32 + koff];
#pragma unroll
      for (int nf = 0; nf < 4; nf++)
        acc[mf][nf] = __builtin_amdgcn_mfma_f32_16x16x32_bf16(bcur[nf], am, acc[mf][nf], 0, 0, 0);
    }
#pragma unroll
    for (int nf = 0; nf < 4; nf++) bcur[nf] = bnxt[nf];
  }

  __syncthreads();  // all As reads done; reuse As as C restage buffer (stride AST)

  // epilogue: bias + relu + stage bf16 to LDS + column stats in regs
#pragma unroll
  for (int nf = 0; nf < 4; nf++) {
    const int c0 = (wcolf + nf) * 16 + grp * 4;
    f32x4 bb = *(const f32x4*)&bias[c0];
    float s[4] = {0.f, 0.f, 0.f, 0.f}, q[4] = {0.f, 0.f, 0.f, 0.f};
#pragma unroll
    for (int mf = 0; mf < MF; mf++) {
      const int r = wrow + mf * 16 + arow;
      unsigned short o[4];
#pragma unroll
      for (int j = 0; j < 4; j++) {
        float v = fmaxf(acc[mf][nf][j] + bb[j], 0.f);
        o[j] = f2bf(v);
        s[j] += v;
        q[j] += v * v;
      }
      *(ushort4w*)&As[r * AST + c0] = *(ushort4w*)o;
    }
#pragma unroll
    for (int d = 1; d < 16; d <<= 1) {
#pragma unroll
      for (int j = 0; j < 4; j++) {
        s[j] += __shfl_xor(s[j], d, 64);
        q[j] += __shfl_xor(q[j], d, 64);
      }
    }
    if ((lane & 15) == 0) {
#pragma unroll
      for (int j = 0; j < 4; j++) {
        atomicAdd(&ssum[c0 + j], s[j]);
        atomicAdd(&ssq[c0 + j], q[j]);
      }
    }
  }
  __syncthreads();

  // coalesced row-major store from LDS (16B/lane) + per-block stats -> replicated copies
  constexpr int CH = N / 8;
  for (int i = tid; i < 64 * CH; i += 256) {
    int row = i / CH, ch = i % CH;
    *(short8*)&Y[(size_t)(brow + row) * 256 + ch * 8] = *(const short8*)&As[row * AST + ch * 8];
  }
  if (tid < N) {
    atomicAdd(&gsum[tid], ssum[tid]);
    atomicAdd(&gsq[tid], ssq[tid]);
  }
}

// ---------- layer 0: embedding gather (bf16 tables, LDS-staged indices) + GEMM ----------
__global__ __launch_bounds__(256, 3) void k_gemm0(const int* __restrict__ x, const unsigned short* __restrict__ tb,
                        const unsigned short* __restrict__ pW, const float* __restrict__ bias,
                        unsigned short* __restrict__ Y, float* __restrict__ stats, int offSum, int offSq) {
  __shared__ unsigned short As[64 * AS0];
  __shared__ int sx[64 * NTAB];
  __shared__ float ssum[256], ssq[256];
  const int tid = threadIdx.x;
  if (tid < 256) { ssum[tid] = 0.f; ssq[tid] = 0.f; }
  const int brow = blockIdx.x * 64;
  // coalesced index stage
  for (int t = tid; t < 64 * NTAB; t += 256) sx[t] = x[brow * NTAB + t];
  // zero K padding cols 272..295
  short8 z8 = {0, 0, 0, 0, 0, 0, 0, 0};
  for (int t = tid; t < 64; t += 256) {
    *(short8*)&As[t * AS0 + 272] = z8;
    *(short8*)&As[t * AS0 + 280] = z8;
    *(short8*)&As[t * AS0 + 288] = z8;
  }
  __syncthreads();
  // gather: 64 rows x 17 tables x 2 half-rows (16B each), direct bf16
  for (int i = tid; i < 64 * NTAB * 2; i += 256) {
    int r = i / (NTAB * 2);
    int rem = i - r * (NTAB * 2);
    int tbl = rem >> 1, half = rem & 1;
    int idx = sx[r * NTAB + tbl];
    short8 v = *(const short8*)&tb[((size_t)(tbl * MAXR + idx)) * 16 + half * 8];
    *(short8*)&As[r * AS0 + tbl * 16 + half * 8] = v;
  }
  __syncthreads();
  float* gsum = stats + (size_t)(blockIdx.x & (NCOPY - 1)) * 1280 + offSum;
  float* gsq  = stats + (size_t)(blockIdx.x & (NCOPY - 1)) * 1280 + offSq;
  gemm_body<9, 256, AS0, 4>(As, pW, bias, Y, brow, ssum, ssq, gsum, gsq);
}

// ---------- mid layers ----------
template <int N, int MF>
__global__ __launch_bounds__(256, 3) void k_gemm_mid(const unsigned short* __restrict__ Yin,
                           const unsigned short* __restrict__ pW, const float* __restrict__ bias,
                           unsigned short* __restrict__ Y, float* __restrict__ stats, int offSum, int offSq) {
  __shared__ unsigned short As[64 * ASM];
  __shared__ float ssum[256], ssq[256];
  const int tid = threadIdx.x;
  if (tid < 256) { ssum[tid] = 0.f; ssq[tid] = 0.f; }
  const int brow = blockIdx.x * 64;
  for (int i = tid; i < 64 * 32; i += 256) {
    int row = i >> 5, c16 = i & 31;
    short8 v = *(const short8*)&Yin[((size_t)(brow + row)) * 256 + c16 * 8];
    *(short8*)&As[row * ASM + c16 * 8] = v;
  }
  __syncthreads();
  float* gsum = stats + (size_t)(blockIdx.x & (NCOPY - 1)) * 1280 + offSum;
  float* gsq  = stats + (size_t)(blockIdx.x & (NCOPY - 1)) * 1280 + offSq;
  gemm_body<8, N, ASM, MF>(As, pW, bias, Y, brow, ssum, ssq, gsum, gsq);
}

// ---------- final dot ----------
__global__ void k_out(const unsigned short* __restrict__ Y, const float* __restrict__ woutp,
                      const float* __restrict__ boutp, float* __restrict__ out) {
  __shared__ float w[128];
  const int tid = threadIdx.x;
  if (tid < 128) w[tid] = woutp[tid];
  __syncthreads();
  const int lane = tid & 63, wave = tid >> 6;
  const int sub = lane & 7, rloc = lane >> 3;
  const int row = blockIdx.x * 32 + wave * 8 + rloc;
  const unsigned short* yr = &Y[(size_t)row * 256 + sub * 16];
  short8 v0 = *(const short8*)yr;
  short8 v1 = *(const short8*)(yr + 8);
  float acc = 0.f;
#pragma unroll
  for (int j = 0; j < 8; j++) acc += bf2f((unsigned short)v0[j]) * w[sub * 16 + j];
#pragma unroll
  for (int j = 0; j < 8; j++) acc += bf2f((unsigned short)v1[j]) * w[sub * 16 + 8 + j];
  acc += __shfl_xor(acc, 1, 64);
  acc += __shfl_xor(acc, 2, 64);
  acc += __shfl_xor(acc, 4, 64);
  if (sub == 0) out[row] = acc + boutp[0];
}

extern "C" void kernel_launch(void* const* d_in, const int* in_sizes, int n_in,
                              void* d_out, int out_size, void* d_ws, size_t ws_size,
                              hipStream_t stream) {
  const int* x = (const int*)d_in[0];
  const float* tables = (const float*)d_in[1];
  const float* W0 = (const float*)d_in[2];
  const float* b0 = (const float*)d_in[3];
  const float* g0 = (const float*)d_in[4];
  const float* be0 = (const float*)d_in[5];
  const float* W1 = (const float*)d_in[6];
  const float* b1 = (const float*)d_in[7];
  const float* g1 = (const float*)d_in[8];
  const float* be1 = (const float*)d_in[9];
  const float* W2 = (const float*)d_in[10];
  const float* b2 = (const float*)d_in[11];
  const float* g2 = (const float*)d_in[12];
  const float* be2 = (const float*)d_in[13];
  const float* Wout = (const float*)d_in[14];
  const float* bout = (const float*)d_in[15];
  float* out = (float*)d_out;

  char* ws = (char*)d_ws;
  unsigned short* Y = (unsigned short*)ws;
  size_t off = (size_t)BR * 256 * 2;  // 134,217,728
  unsigned short* pW0 = (unsigned short*)(ws + off); off += (size_t)9 * 16 * 64 * 8 * 2;
  unsigned short* pW1 = (unsigned short*)(ws + off); off += (size_t)8 * 16 * 64 * 8 * 2;
  unsigned short* pW2 = (unsigned short*)(ws + off); off += (size_t)8 * 8 * 64 * 8 * 2;
  float* b1p = (float*)(ws + off); off += 1024;
  float* b2p = (float*)(ws + off); off += 512;
  float* woutp = (float*)(ws + off); off += 512;
  float* boutp = (float*)(ws + off); off += 256;
  float* stats = (float*)(ws + off); off += (size_t)NCOPY * 1280 * 4;
  unsigned short* tb = (unsigned short*)(ws + off); off += (size_t)17 * MAXR * 16 * 2;  // 278528

  // stats offsets within each 1280-float copy
  const int oS0 = 0, oQ0 = 256, oS1 = 512, oQ1 = 768, oS2 = 1024, oQ2 = 1152;

  k_prep0<<<64, 256, 0, stream>>>(W0, tables, pW0, tb, stats);
  k_gemm0<<<BR / 64, 256, 0, stream>>>(x, tb, pW0, b0, Y, stats, oS0, oQ0);
  k_fold<256, 256><<<16, 256, 0, stream>>>(stats, oS0, oQ0, g0, be0, W1, b1, pW1, b1p);
  k_gemm_mid<256, 4><<<BR / 64, 256, 0, stream>>>(Y, pW1, b1p, Y, stats, oS1, oQ1);
  k_fold<256, 128><<<16, 256, 0, stream>>>(stats, oS1, oQ1, g1, be1, W2, b2, pW2, b2p);
  k_gemm_mid<128, 2><<<BR / 64, 256, 0, stream>>>(Y, pW2, b2p, Y, stats, oS2, oQ2);
  k_foldout<<<1, 128, 0, stream>>>(stats, oS2, oQ2, g2, be2, Wout, bout, woutp, boutp);
  k_out<<<BR / 32, 256, 0, stream>>>(Y, woutp, boutp, out);
}